// Round 5
// baseline (269.304 us; speedup 1.0000x reference)
//
#include <hip/hip_runtime.h>

// SLAM layer: out[1,T,M,E,1] = (main[T,M,K] @ relu(x_aux[K,T,Da] @ W[Da,E] + b)[K,T,E] per t)
// T=128, M=512, K=256, Da=256, E=512.
// R5: R4 with the staging-address bug fixed (MS_LOAD was missing mb -> wrong x_main rows
// for 3/4 of blocks). Structure otherwise identical: fused f32->bf16 LDS staging in main,
// double-buffered, issue-early loads; aux/wchunk unchanged from R3 (verified passing).

typedef __attribute__((ext_vector_type(8))) short  bf16x8;   // MFMA A/B frag (4 VGPR)
typedef __attribute__((ext_vector_type(4))) float  f32x4;    // MFMA C/D frag
typedef __attribute__((ext_vector_type(4))) unsigned int uint4v;
typedef __attribute__((ext_vector_type(2))) unsigned int uint2v;

#define T_DIM 128
#define M_DIM 512
#define K_DIM 256
#define DA    256
#define DENSE 512
// auxc chunk layout (bf16): (t,k,e) -> t*131072 + (k>>3)*4096 + e*8 + (k&7)
#define CHUNK_T_STRIDE 131072
#define CHUNK_G_STRIDE 4096

__device__ __forceinline__ unsigned short f2bf(float f) {
    unsigned u = __builtin_bit_cast(unsigned, f);
    unsigned r = (u + 0x7fffu + ((u >> 16) & 1u)) >> 16;   // RNE
    return (unsigned short)r;
}
__device__ __forceinline__ unsigned pack2(float lo, float hi) {
    return (unsigned)f2bf(lo) | ((unsigned)f2bf(hi) << 16);
}

// ---------------- Kernel 0: W [Da][E] f32 -> Wc bf16 chunks [g=Da/8][E][8] ----------------
__global__ __launch_bounds__(256) void wchunk_kernel(const float* __restrict__ W,
                                                     unsigned short* __restrict__ Wc) {
    int c = blockIdx.x * 256 + threadIdx.x;   // chunk id = g*DENSE + e
    int g = c >> 9;
    int e = c & 511;
    float f[8];
#pragma unroll
    for (int j = 0; j < 8; ++j) f[j] = W[(g * 8 + j) * DENSE + e];
    uint4v w;
    w.x = pack2(f[0], f[1]); w.y = pack2(f[2], f[3]);
    w.z = pack2(f[4], f[5]); w.w = pack2(f[6], f[7]);
    *reinterpret_cast<uint4v*>(Wc + (size_t)c * 8) = w;
}

// ---------------- Kernel 1: aux GEMM (unchanged from R3, verified) -------------------------
__global__ __launch_bounds__(256) void aux_kernel(const float* __restrict__ xaux,
                                                  const unsigned short* __restrict__ Wc,
                                                  const float* __restrict__ bias,
                                                  unsigned short* __restrict__ auxc) {
    __shared__ unsigned short xa[64 * 264];   // 33792 B, 528B row stride
    const int bid = blockIdx.x;               // 1024 blocks
    const int swz = (bid & 7) * 128 + (bid >> 3);   // XCD-grouped, bijective
    const int t  = swz >> 3;
    const int r  = swz & 7;
    const int kb = (r >> 1) * 64;
    const int eb = (r & 1) * 256;
    const int tid = threadIdx.x, lane = tid & 63, wid = tid >> 6;
    const int l15 = lane & 15, lg = lane >> 4;
    char* xab = reinterpret_cast<char*>(xa);

#pragma unroll
    for (int j = 0; j < 16; ++j) {
        int kr = wid + 4 * j;
        const float* src = xaux + ((size_t)(kb + kr) * T_DIM + t) * DA + lane * 4;
        f32x4 v = *reinterpret_cast<const f32x4*>(src);
        uint2v o; o.x = pack2(v.x, v.y); o.y = pack2(v.z, v.w);
        *reinterpret_cast<uint2v*>(xab + kr * 528 + lane * 8) = o;
    }
    __syncthreads();

    const int we = wid * 64;
    f32x4 acc[4][4];
#pragma unroll
    for (int i = 0; i < 4; ++i)
#pragma unroll
        for (int j = 0; j < 4; ++j) acc[i][j] = (f32x4)0.0f;

#define AUX_LOAD_WF(dst, dsv)                                                              \
    do {                                                                                   \
        _Pragma("unroll") for (int j = 0; j < 4; ++j) {                                    \
            int e = eb + we + j * 16 + l15;                                                \
            dst[j] = *reinterpret_cast<const bf16x8*>(                                     \
                Wc + (size_t)((dsv) * 4 + lg) * CHUNK_G_STRIDE + (size_t)e * 8);           \
        }                                                                                  \
    } while (0)

#define AUX_COMPUTE(wfc, dsv)                                                              \
    do {                                                                                   \
        bf16x8 xf[4];                                                                      \
        _Pragma("unroll") for (int i = 0; i < 4; ++i)                                      \
            xf[i] = *reinterpret_cast<const bf16x8*>(                                      \
                xab + (i * 16 + l15) * 528 + ((dsv) * 4 + lg) * 16);                       \
        _Pragma("unroll") for (int i = 0; i < 4; ++i)                                      \
            _Pragma("unroll") for (int j = 0; j < 4; ++j)                                  \
                acc[i][j] = __builtin_amdgcn_mfma_f32_16x16x32_bf16(xf[i], wfc[j], acc[i][j], 0, 0, 0); \
    } while (0)

    bf16x8 wfA[4], wfB[4];
    AUX_LOAD_WF(wfA, 0);
#pragma unroll
    for (int ds = 0; ds < 8; ds += 2) {
        AUX_LOAD_WF(wfB, ds + 1);
        AUX_COMPUTE(wfA, ds);
        if (ds + 2 < 8) { AUX_LOAD_WF(wfA, ds + 2); }
        AUX_COMPUTE(wfB, ds + 1);
    }
#undef AUX_LOAD_WF
#undef AUX_COMPUTE

#pragma unroll
    for (int i = 0; i < 4; ++i) {
        int k0 = kb + i * 16 + lg * 4;        // 4 consecutive k; k0&7 in {0,4}
#pragma unroll
        for (int j = 0; j < 4; ++j) {
            int e = eb + we + j * 16 + l15;
            float bv = bias[e];
            float v0 = fmaxf(acc[i][j].x + bv, 0.0f);
            float v1 = fmaxf(acc[i][j].y + bv, 0.0f);
            float v2 = fmaxf(acc[i][j].z + bv, 0.0f);
            float v3 = fmaxf(acc[i][j].w + bv, 0.0f);
            uint2 o; o.x = pack2(v0, v1); o.y = pack2(v2, v3);
            size_t idx = (size_t)t * CHUNK_T_STRIDE + (size_t)(k0 >> 3) * CHUNK_G_STRIDE
                       + (size_t)e * 8 + (k0 & 7);
            *reinterpret_cast<uint2*>(auxc + idx) = o;
        }
    }
}

// ---------------- Kernel 2: main GEMM v5 (fused x_main staging, mb fix) --------------------
// D[e][m] = sum_k auxc[k][e] * x_main[t][mb+m][k]. A-op = auxc chunks (global, L2-served).
// B-op = x_main staged f32->bf16 via LDS per 32-k step, double-buffered, issue-early.
// LDS row stride 72B (18 dwords mod 32 -> 16 distinct even bank starts, 2-way = free).
#define MS_STRIDE 72                       // bytes per m-row (64B data + 8B pad)
#define MS_BUF    (128 * MS_STRIDE)        // 9216 B per buffer
__global__ __launch_bounds__(256) void main_kernel(const float* __restrict__ xmain,
                                                   const unsigned short* __restrict__ auxc,
                                                   float* __restrict__ out) {
    __shared__ char ms[2 * MS_BUF];                  // 18.4 KB
    const int bid = blockIdx.x;                      // 2048 blocks
    const int swz = ((bid & 7) << 8) | (bid >> 3);   // XCD-grouped, bijective
    const int t   = swz >> 4;
    const int r4  = swz & 15;
    const int eb  = (r4 & 3) * 128;
    const int mb  = (r4 >> 2) * 128;
    const int tid  = threadIdx.x;
    const int lane = tid & 63, wid = tid >> 6;
    const int wm = (wid & 1) * 64;
    const int we = (wid >> 1) * 64;
    const int l15 = lane & 15, lg = lane >> 4;

    const float* At = xmain + (size_t)t * M_DIM * K_DIM;            // rows m, k contiguous
    const unsigned short* Ct = auxc + (size_t)t * CHUNK_T_STRIDE;   // A-op rows = e

    // staging role: thread covers rows mb + (p*32 + tid>>3), k-bytes (tid&7)*16 per 32k step
    const int srow = tid >> 3;            // 0..31 (+32 per p)
    const int skof = tid & 7;             // octet-of-4-floats within 32k

    f32x4 acc[4][4];
#pragma unroll
    for (int i = 0; i < 4; ++i)
#pragma unroll
        for (int j = 0; j < 4; ++j) acc[i][j] = (f32x4)0.0f;

#define MS_LOAD(regs, ksv)                                                                 \
    do {                                                                                   \
        _Pragma("unroll") for (int p = 0; p < 4; ++p)                                      \
            regs[p] = *reinterpret_cast<const f32x4*>(                                     \
                At + (size_t)(mb + p * 32 + srow) * K_DIM + (ksv) * 32 + skof * 4);        \
    } while (0)

#define MS_WRITE(regs, bufv)                                                               \
    do {                                                                                   \
        _Pragma("unroll") for (int p = 0; p < 4; ++p) {                                    \
            uint2v o;                                                                      \
            o.x = pack2(regs[p].x, regs[p].y);                                             \
            o.y = pack2(regs[p].z, regs[p].w);                                             \
            *reinterpret_cast<uint2v*>(ms + (bufv) * MS_BUF                                \
                                          + (p * 32 + srow) * MS_STRIDE + skof * 8) = o;   \
        }                                                                                  \
    } while (0)

    f32x4 sreg[4];
    MS_LOAD(sreg, 0);
    MS_WRITE(sreg, 0);
    __syncthreads();

#pragma unroll
    for (int ks = 0; ks < 8; ++ks) {
        const int cur = ks & 1;
        if (ks < 7) MS_LOAD(sreg, ks + 1);            // issue next-step loads early

        bf16x8 af[4], mf[4];
#pragma unroll
        for (int i = 0; i < 4; ++i)
            af[i] = *reinterpret_cast<const bf16x8*>(
                Ct + (size_t)(ks * 4 + lg) * CHUNK_G_STRIDE
                   + (size_t)(eb + we + i * 16 + l15) * 8);
#pragma unroll
        for (int j = 0; j < 4; ++j)
            mf[j] = *reinterpret_cast<const bf16x8*>(
                ms + cur * MS_BUF + (wm + j * 16 + l15) * MS_STRIDE + lg * 16);
#pragma unroll
        for (int i = 0; i < 4; ++i)
#pragma unroll
            for (int j = 0; j < 4; ++j)
                acc[i][j] = __builtin_amdgcn_mfma_f32_16x16x32_bf16(af[i], mf[j], acc[i][j], 0, 0, 0);

        if (ks < 7) {
            MS_WRITE(sreg, cur ^ 1);                  // fill other buffer
            __syncthreads();                          // ready for next step
        }
    }
#undef MS_LOAD
#undef MS_WRITE

#pragma unroll
    for (int i = 0; i < 4; ++i) {
        int e0 = eb + we + i * 16 + lg * 4;   // 4 consecutive e -> float4 store
#pragma unroll
        for (int j = 0; j < 4; ++j) {
            int m = mb + wm + j * 16 + l15;
            *reinterpret_cast<f32x4*>(out + (size_t)t * M_DIM * DENSE + (size_t)m * DENSE + e0) = acc[i][j];
        }
    }
}

extern "C" void kernel_launch(void* const* d_in, const int* in_sizes, int n_in,
                              void* d_out, int out_size, void* d_ws, size_t ws_size,
                              hipStream_t stream) {
    const float* x_main = (const float*)d_in[0];   // [1,128,512,256]
    const float* x_aux  = (const float*)d_in[1];   // [256,128,256]
    const float* W      = (const float*)d_in[2];   // [256,512]
    const float* b      = (const float*)d_in[3];   // [512]
    float* out = (float*)d_out;                    // [1,128,512,512,1]

    // ws layout: Wc 256KiB @0 ; auxc 32MiB @ 1<<19. Total 32.5 MiB.
    unsigned short* Wc   = (unsigned short*)d_ws;
    unsigned short* auxc = (unsigned short*)((char*)d_ws + (1u << 19));

    wchunk_kernel<<<64, 256, 0, stream>>>(W, Wc);
    aux_kernel<<<1024, 256, 0, stream>>>(x_aux, Wc, b, auxc);
    main_kernel<<<2048, 256, 0, stream>>>(x_main, auxc, out);
}